// Round 8
// baseline (272.921 us; speedup 1.0000x reference)
//
#include <hip/hip_runtime.h>

#define NN 50000
#define NE 800000
#define DD 256
#define DE_DIM 16
#define HH 4
#define FF 32
#define HF 128
#define OUTD 32
#define SLOPE 0.2f
#define NB_SCAN ((NN + 255) / 256)   // 196

// MFMA proj tiling
#define BM 64
#define NCOL 272          // 128 + 128 + 4 + 4 + 8 pad
#define APAD 264          // A LDS row stride (bf16): 528B -> 2-way on frag reads (free)
// node_final MFMA tiling
#define NFB 64            // nodes per block
#define FPAD 136          // LDS row stride (bf16)

typedef short short8 __attribute__((ext_vector_type(8)));
typedef float f32x4 __attribute__((ext_vector_type(4)));
typedef unsigned short us4 __attribute__((ext_vector_type(4)));

// fp32 -> bf16 bits, round-to-nearest-even
__device__ __forceinline__ unsigned short bf16r(float x) {
  unsigned u = __float_as_uint(x);
  u += 0x7FFFu + ((u >> 16) & 1u);
  return (unsigned short)(u >> 16);
}

// ---- Prep: assemble transposed bf16 weight panel Bt[272][256] ----
__global__ __launch_bounds__(256) void bt_prep_kernel(
    const float* __restrict__ Wsrc, const float* __restrict__ Wdst,
    const float* __restrict__ Wasrc, const float* __restrict__ Wadst,
    unsigned short* __restrict__ Bt)
{
  int c = blockIdx.x;     // 0..271
  int k = threadIdx.x;    // 0..255
  float v = 0.f;
  if (c < 128)      v = Wsrc[(size_t)k * HF + c];
  else if (c < 256) v = Wdst[(size_t)k * HF + (c - 128)];
  else if (c < 260) v = Wasrc[(size_t)k * HH + (c - 256)];
  else if (c < 264) v = Wadst[(size_t)k * HH + (c - 260)];
  Bt[(size_t)c * DD + k] = bf16r(v);
}

// ---- Prep: transposed bf16 W_agg [128][128] and W_apply [32][128] ----
__global__ __launch_bounds__(128) void wfin_prep_kernel(
    const float* __restrict__ W_agg, const float* __restrict__ W_apply,
    unsigned short* __restrict__ Wagg_t, unsigned short* __restrict__ Wapp_t)
{
  int c = blockIdx.x;     // 0..159
  int k = threadIdx.x;    // 0..127
  if (c < 128) Wagg_t[(size_t)c * HF + k] = bf16r(W_agg[(size_t)k * HF + c]);
  else         Wapp_t[(size_t)(c - 128) * HF + k] = bf16r(W_apply[(size_t)k * OUTD + (c - 128)]);
}

// ---- Kernel 1'': node projections via bf16 MFMA; B read direct from L2 ----
// A panel staged once in LDS -> registers; per col-tile: 8 global B loads,
// 8 MFMAs, immediate store. No per-K-step barriers, no B LDS buffer.
__global__ __launch_bounds__(256) void mfma_proj_kernel(
    const float* __restrict__ feat, const unsigned short* __restrict__ Bt,
    const float* __restrict__ bdst,
    float* __restrict__ fc_src, float* __restrict__ fc_dst,
    float* __restrict__ asrc, float* __restrict__ adst)
{
  __shared__ unsigned short Albuf[BM * APAD];      // 33792 B
  const int tid  = threadIdx.x;
  const int wave = tid >> 6, lane = tid & 63;
  const int m0 = blockIdx.x * BM;

  // stage A panel [64][256] fp32->bf16 (coalesced float4 global reads)
  for (int i = tid; i < BM * 64; i += 256) {
    int r = i >> 6, c4 = i & 63;
    int gr = m0 + r; if (gr >= NN) gr = NN - 1;
    float4 v = *(const float4*)(feat + (size_t)gr * DD + c4 * 4);
    us4 b; b.x = bf16r(v.x); b.y = bf16r(v.y); b.z = bf16r(v.z); b.w = bf16r(v.w);
    *(us4*)&Albuf[r * APAD + c4 * 4] = b;
  }
  __syncthreads();

  const int arow = wave * 16 + (lane & 15);
  const int koff = (lane >> 4) * 8;
  const int cl = lane & 15;
  const int rbase = m0 + wave * 16 + (lane >> 4) * 4;

  // A fragments for all 8 K-steps -> registers (read LDS once)
  short8 afrag[8];
#pragma unroll
  for (int kk = 0; kk < 8; ++kk)
    afrag[kk] = *(const short8*)&Albuf[arow * APAD + kk * 32 + koff];

#pragma unroll
  for (int c0 = 0; c0 < 17; ++c0) {
    const unsigned short* brow = Bt + (size_t)(c0 * 16 + cl) * DD + koff;
    short8 bfrag[8];
#pragma unroll
    for (int kk = 0; kk < 8; ++kk)
      bfrag[kk] = *(const short8*)(brow + kk * 32);

    f32x4 acc = (f32x4){0.f, 0.f, 0.f, 0.f};
#pragma unroll
    for (int kk = 0; kk < 8; ++kk)
      acc = __builtin_amdgcn_mfma_f32_16x16x32_bf16(afrag[kk], bfrag[kk], acc, 0, 0, 0);

    int gcol = c0 * 16 + cl;
#pragma unroll
    for (int j = 0; j < 4; ++j) {
      int grow = rbase + j;
      if (grow >= NN) continue;
      float v = acc[j];
      if (gcol < 128)      fc_src[(size_t)grow * HF + gcol] = v;
      else if (gcol < 256) fc_dst[(size_t)grow * HF + (gcol - 128)] = v + bdst[gcol - 128];
      else if (gcol < 260) asrc[(size_t)grow * HH + (gcol - 256)] = v;
      else if (gcol < 264) adst[(size_t)grow * HH + (gcol - 260)] = v;
    }
  }
}

// ---- dst-degree histogram + per-edge rank (CSR slot precompute) ----
__global__ __launch_bounds__(256) void hist_kernel(
    const int* __restrict__ dst_idx, int* __restrict__ cnt,
    int* __restrict__ rank)
{
  int e = blockIdx.x * 256 + threadIdx.x;
  if (e < NE) rank[e] = atomicAdd(&cnt[dst_idx[e]], 1);
}

// ---- CSR scan: block-local exclusive scan ----
__global__ __launch_bounds__(256) void scan_block_kernel(
    const int* __restrict__ cnt, int* __restrict__ offs, int* __restrict__ bsum)
{
  __shared__ int tmp[256];
  int t = threadIdx.x;
  int i = blockIdx.x * 256 + t;
  int v = (i < NN) ? cnt[i] : 0;
  tmp[t] = v;
  __syncthreads();
  for (int ofs = 1; ofs < 256; ofs <<= 1) {
    int add = (t >= ofs) ? tmp[t - ofs] : 0;
    __syncthreads();
    tmp[t] += add;
    __syncthreads();
  }
  if (i < NN) offs[i] = tmp[t] - v;
  if (t == 255) bsum[blockIdx.x] = tmp[255];
}

__global__ __launch_bounds__(256) void scan_bsum_kernel(
    const int* __restrict__ bsum, int* __restrict__ boff)
{
  __shared__ int tmp[256];
  int t = threadIdx.x;
  int v = (t < NB_SCAN) ? bsum[t] : 0;
  tmp[t] = v;
  __syncthreads();
  for (int ofs = 1; ofs < 256; ofs <<= 1) {
    int add = (t >= ofs) ? tmp[t - ofs] : 0;
    __syncthreads();
    tmp[t] += add;
    __syncthreads();
  }
  if (t < NB_SCAN) boff[t] = tmp[t] - v;
}

__global__ __launch_bounds__(256) void scan_final_kernel(
    int* __restrict__ offs, const int* __restrict__ boff)
{
  int i = blockIdx.x * 256 + threadIdx.x;
  if (i < NN) offs[i] += boff[blockIdx.x];
  if (i == 0) offs[NN] = NE;
}

// ---- fused: per-edge logits + scatter into CSR slot (no atomics) ----
__global__ __launch_bounds__(256) void scatter_logits_kernel(
    const float* __restrict__ feat_edge, const float* __restrict__ Wae, // [16,4]
    const int* __restrict__ src_idx, const int* __restrict__ dst_idx,
    const float* __restrict__ asrc, const float* __restrict__ adst,
    const int* __restrict__ offs, const int* __restrict__ rank,
    int* __restrict__ src_sorted, float* __restrict__ esorted)
{
  int e = blockIdx.x * 256 + threadIdx.x;
  if (e >= NE) return;
  int s = src_idx[e], d = dst_idx[e];

  float ae[HH] = {0.f, 0.f, 0.f, 0.f};
  const float4* fe4 = (const float4*)(feat_edge + (size_t)e * DE_DIM);
#pragma unroll
  for (int q = 0; q < 4; ++q) {
    float4 x = fe4[q];
    const float xs[4] = {x.x, x.y, x.z, x.w};
#pragma unroll
    for (int kk = 0; kk < 4; ++kk) {
      int k = q * 4 + kk;
#pragma unroll
      for (int h = 0; h < HH; ++h) ae[h] += xs[kk] * Wae[k * HH + h];
    }
  }
  float as[4], ad[4];
  *(float4*)as = *(const float4*)(asrc + (size_t)s * 4);
  *(float4*)ad = *(const float4*)(adst + (size_t)d * 4);

  float ev[4];
#pragma unroll
  for (int h = 0; h < HH; ++h) {
    float v = as[h] + ad[h] + ae[h];
    ev[h] = v >= 0.f ? v : SLOPE * v;
  }
  int p = offs[d] + rank[e];
  src_sorted[p] = s;
  *(float4*)(esorted + (size_t)p * 4) = *(float4*)ev;
}

// ---- fused segment softmax + aggregation: one wave per dst node ----
__global__ __launch_bounds__(64) void agg_fused_kernel(
    const int* __restrict__ offs, const int* __restrict__ src_sorted,
    const float* __restrict__ esorted, const float* __restrict__ fc_src,
    float* __restrict__ h_out)
{
  const int d = blockIdx.x;
  const int t = threadIdx.x;        // 0..63
  const int fpair = t << 1;         // feature base (even)
  const int h = t >> 4;             // head, 16 lanes each
  const int beg = offs[d], end = offs[d + 1];

  float m = -3.4e38f;
  for (int p = beg + (t & 15); p < end; p += 16)
    m = fmaxf(m, esorted[(size_t)p * 4 + h]);
#pragma unroll
  for (int ofs = 1; ofs < 16; ofs <<= 1)
    m = fmaxf(m, __shfl_xor(m, ofs, 16));

  float ssum = 0.f;
  float accx = 0.f, accy = 0.f;
  int p = beg;
  for (; p + 4 <= end; p += 4) {
    int s0 = src_sorted[p + 0];
    int s1 = src_sorted[p + 1];
    int s2 = src_sorted[p + 2];
    int s3 = src_sorted[p + 3];
    float e0 = esorted[(size_t)(p + 0) * 4 + h];
    float e1 = esorted[(size_t)(p + 1) * 4 + h];
    float e2 = esorted[(size_t)(p + 2) * 4 + h];
    float e3 = esorted[(size_t)(p + 3) * 4 + h];
    float2 fa = *(const float2*)&fc_src[(size_t)s0 * HF + fpair];
    float2 fb = *(const float2*)&fc_src[(size_t)s1 * HF + fpair];
    float2 fc_ = *(const float2*)&fc_src[(size_t)s2 * HF + fpair];
    float2 fd = *(const float2*)&fc_src[(size_t)s3 * HF + fpair];
    float z0 = __expf(e0 - m), z1 = __expf(e1 - m);
    float z2 = __expf(e2 - m), z3 = __expf(e3 - m);
    ssum += (z0 + z1) + (z2 + z3);
    accx += fa.x * z0 + fb.x * z1 + fc_.x * z2 + fd.x * z3;
    accy += fa.y * z0 + fb.y * z1 + fc_.y * z2 + fd.y * z3;
  }
  for (; p < end; ++p) {
    int s = src_sorted[p];
    float z = __expf(esorted[(size_t)p * 4 + h] - m);
    float2 f = *(const float2*)&fc_src[(size_t)s * HF + fpair];
    ssum += z;
    accx += f.x * z;
    accy += f.y * z;
  }
  float inv = (end > beg) ? 1.f / ssum : 0.f;
  float2 r; r.x = accx * inv; r.y = accy * inv;
  *(float2*)&h_out[(size_t)d * HF + fpair] = r;
}

// ---- Kernel 5': LN + MFMA(W_agg) + residual/leaky + MFMA(W_apply) ----
__global__ __launch_bounds__(256) void node_final_mfma_kernel(
    const float* __restrict__ h_in, const float* __restrict__ scale,
    const float* __restrict__ offset,
    const unsigned short* __restrict__ Wagg_t, const float* __restrict__ b_agg,
    const float* __restrict__ fc_dst,
    const unsigned short* __restrict__ Wapp_t, const float* __restrict__ b_apply,
    float* __restrict__ out)
{
  __shared__ unsigned short Abuf[NFB * FPAD];     // 17408 B
  __shared__ unsigned short A2buf[NFB * FPAD];    // 17408 B
  __shared__ unsigned short Bagg[HF * FPAD];      // 34816 B
  __shared__ unsigned short Bapp[OUTD * FPAD];    // 8704 B
  const int tid = threadIdx.x;
  const int wave = tid >> 6, lane = tid & 63;
  const int n0 = blockIdx.x * NFB;

  for (int i = tid; i < HF * 16; i += 256) {
    int c = i >> 4, q = i & 15;
    *(short8*)&Bagg[c * FPAD + q * 8] = *(const short8*)(Wagg_t + (size_t)c * HF + q * 8);
  }
  for (int i = tid; i < OUTD * 16; i += 256) {
    int c = i >> 4, q = i & 15;
    *(short8*)&Bapp[c * FPAD + q * 8] = *(const short8*)(Wapp_t + (size_t)c * HF + q * 8);
  }

  {
    const int half = tid >> 7;        // 0/1
    const int t = tid & 127;          // feature
    const float sc = scale[t], of = offset[t];
    for (int nn = 0; nn < 32; ++nn) {
      int row = half * 32 + nn;
      int node = n0 + row; if (node >= NN) node = NN - 1;
      float v = h_in[(size_t)node * HF + t];
      float sum = v;
#pragma unroll
      for (int m = 1; m < 32; m <<= 1) sum += __shfl_xor(sum, m);
      float mean = sum * (1.f / 32.f);
      float dv = v - mean;
      float v2 = dv * dv;
#pragma unroll
      for (int m = 1; m < 32; m <<= 1) v2 += __shfl_xor(v2, m);
      float var = v2 * (1.f / 32.f) + 1e-9f;
      Abuf[row * FPAD + t] = bf16r(dv * sc * rsqrtf(var) + of);
    }
  }
  __syncthreads();

  const int arow = wave * 16 + (lane & 15);
  const int koff = (lane >> 4) * 8;
  const int rbase = wave * 16 + (lane >> 4) * 4;
  const int cl = lane & 15;

  f32x4 acc1[8];
#pragma unroll
  for (int c0 = 0; c0 < 8; ++c0) acc1[c0] = (f32x4){0.f, 0.f, 0.f, 0.f};
#pragma unroll
  for (int ks = 0; ks < 4; ++ks) {
    short8 a = *(const short8*)&Abuf[arow * FPAD + ks * 32 + koff];
#pragma unroll
    for (int c0 = 0; c0 < 8; ++c0) {
      short8 b = *(const short8*)&Bagg[(c0 * 16 + cl) * FPAD + ks * 32 + koff];
      acc1[c0] = __builtin_amdgcn_mfma_f32_16x16x32_bf16(a, b, acc1[c0], 0, 0, 0);
    }
  }

#pragma unroll
  for (int c0 = 0; c0 < 8; ++c0) {
    int gcol = c0 * 16 + cl;
    float bg = b_agg[gcol];
#pragma unroll
    for (int j = 0; j < 4; ++j) {
      int row = rbase + j;
      int grow = n0 + row;
      float fd = (grow < NN) ? fc_dst[(size_t)grow * HF + gcol] : 0.f;
      float r = acc1[c0][j] + bg + fd;
      A2buf[row * FPAD + gcol] = bf16r(r >= 0.f ? r : SLOPE * r);
    }
  }
  __syncthreads();

  f32x4 acc2[2];
#pragma unroll
  for (int c0 = 0; c0 < 2; ++c0) acc2[c0] = (f32x4){0.f, 0.f, 0.f, 0.f};
#pragma unroll
  for (int ks = 0; ks < 4; ++ks) {
    short8 a = *(const short8*)&A2buf[arow * FPAD + ks * 32 + koff];
#pragma unroll
    for (int c0 = 0; c0 < 2; ++c0) {
      short8 b = *(const short8*)&Bapp[(c0 * 16 + cl) * FPAD + ks * 32 + koff];
      acc2[c0] = __builtin_amdgcn_mfma_f32_16x16x32_bf16(a, b, acc2[c0], 0, 0, 0);
    }
  }
#pragma unroll
  for (int c0 = 0; c0 < 2; ++c0) {
    int gcol = c0 * 16 + cl;
    float ba = b_apply[gcol];
#pragma unroll
    for (int j = 0; j < 4; ++j) {
      int grow = n0 + rbase + j;
      if (grow < NN) out[(size_t)grow * OUTD + gcol] = acc2[c0][j] + ba;
    }
  }
}

extern "C" void kernel_launch(void* const* d_in, const int* in_sizes, int n_in,
                              void* d_out, int out_size, void* d_ws, size_t ws_size,
                              hipStream_t stream)
{
  const float* feat_src    = (const float*)d_in[0];
  const float* feat_edge   = (const float*)d_in[1];
  const int*   src_idx     = (const int*)d_in[2];
  const int*   dst_idx     = (const int*)d_in[3];
  const float* W_src       = (const float*)d_in[4];
  const float* W_attn_src  = (const float*)d_in[5];
  const float* W_attn_dst  = (const float*)d_in[6];
  const float* W_attn_edge = (const float*)d_in[7];
  const float* scale       = (const float*)d_in[8];
  const float* offset      = (const float*)d_in[9];
  const float* W_agg       = (const float*)d_in[10];
  const float* b_agg       = (const float*)d_in[11];
  const float* W_dst       = (const float*)d_in[12];
  const float* b_dst       = (const float*)d_in[13];
  const float* W_apply     = (const float*)d_in[14];
  const float* b_apply     = (const float*)d_in[15];
  float* out = (float*)d_out;

  char* ws = (char*)d_ws;
  size_t off = 0;
  auto take = [&](size_t bytes) {
    size_t o = off;
    off = (off + bytes + 255) & ~(size_t)255;
    return o;
  };
  size_t fc_src_off = take((size_t)NN * HF * 4);
  size_t fc_dst_off = take((size_t)NN * HF * 4);
  size_t asrc_off   = take((size_t)NN * 4 * 4);
  size_t adst_off   = take((size_t)NN * 4 * 4);
  size_t bt_off     = take((size_t)NCOL * DD * 2);
  size_t wagg_off   = take((size_t)HF * HF * 2);
  size_t wapp_off   = take((size_t)OUTD * HF * 2);
  size_t cnt_off    = take((size_t)NN * 4);       // zeroed
  size_t offs_off   = take((size_t)(NN + 1) * 4);
  size_t bsum_off   = take((size_t)NB_SCAN * 4);
  size_t boff_off   = take((size_t)NB_SCAN * 4);
  size_t rank_off   = take((size_t)NE * 4);
  size_t ssort_off  = take((size_t)NE * 4);
  size_t esort_off  = take((size_t)NE * 4 * 4);
  size_t hout_off   = take((size_t)NN * HF * 4);
  if (ws_size < off) return;  // workspace too small -> loud failure

  float*          fc_src     = (float*)(ws + fc_src_off);
  float*          fc_dst     = (float*)(ws + fc_dst_off);
  float*          asrc       = (float*)(ws + asrc_off);
  float*          adst       = (float*)(ws + adst_off);
  unsigned short* Bt         = (unsigned short*)(ws + bt_off);
  unsigned short* Wagg_t     = (unsigned short*)(ws + wagg_off);
  unsigned short* Wapp_t     = (unsigned short*)(ws + wapp_off);
  int*            cnt        = (int*)(ws + cnt_off);
  int*            offs       = (int*)(ws + offs_off);
  int*            bsum       = (int*)(ws + bsum_off);
  int*            boff       = (int*)(ws + boff_off);
  int*            rank       = (int*)(ws + rank_off);
  int*            src_sorted = (int*)(ws + ssort_off);
  float*          esorted    = (float*)(ws + esort_off);
  float*          h_out      = (float*)(ws + hout_off);

  hipMemsetAsync(ws + cnt_off, 0, (size_t)NN * 4, stream);

  bt_prep_kernel<<<NCOL, 256, 0, stream>>>(W_src, W_dst, W_attn_src, W_attn_dst, Bt);
  wfin_prep_kernel<<<160, 128, 0, stream>>>(W_agg, W_apply, Wagg_t, Wapp_t);

  hist_kernel<<<(NE + 255) / 256, 256, 0, stream>>>(dst_idx, cnt, rank);

  mfma_proj_kernel<<<(NN + BM - 1) / BM, 256, 0, stream>>>(
      feat_src, Bt, b_dst, fc_src, fc_dst, asrc, adst);

  scan_block_kernel<<<NB_SCAN, 256, 0, stream>>>(cnt, offs, bsum);
  scan_bsum_kernel<<<1, 256, 0, stream>>>(bsum, boff);
  scan_final_kernel<<<NB_SCAN, 256, 0, stream>>>(offs, boff);

  scatter_logits_kernel<<<(NE + 255) / 256, 256, 0, stream>>>(
      feat_edge, W_attn_edge, src_idx, dst_idx, asrc, adst,
      offs, rank, src_sorted, esorted);

  agg_fused_kernel<<<NN, 64, 0, stream>>>(
      offs, src_sorted, esorted, fc_src, h_out);

  node_final_mfma_kernel<<<(NN + NFB - 1) / NFB, 256, 0, stream>>>(
      h_out, scale, offset, Wagg_t, b_agg, fc_dst, Wapp_t, b_apply, out);
}

// Round 9
// 231.743 us; speedup vs baseline: 1.1777x; 1.1777x over previous
//
#include <hip/hip_runtime.h>

#define NN 50000
#define NE 800000
#define DD 256
#define DE_DIM 16
#define HH 4
#define FF 32
#define HF 128
#define OUTD 32
#define SLOPE 0.2f
#define NB_SCAN ((NN + 255) / 256)   // 196

// MFMA proj tiling
#define BM 64
#define NCOL 272          // 128 + 128 + 4 + 4 + 8 pad
#define APAD 264          // A LDS row stride (bf16): 528B -> 2-way on frag reads (free)
#define BTPAD 40          // Bt LDS row stride (bf16): 80B (R7-verified read path)
#define TILE_S8 1088      // short8 chunks per 272x32 K-tile
// node_final MFMA tiling
#define NFB 64            // nodes per block
#define FPAD 136          // LDS row stride (bf16)

typedef short short8 __attribute__((ext_vector_type(8)));
typedef float f32x4 __attribute__((ext_vector_type(4)));
typedef unsigned short us4 __attribute__((ext_vector_type(4)));

// fp32 -> bf16 bits, round-to-nearest-even
__device__ __forceinline__ unsigned short bf16r(float x) {
  unsigned u = __float_as_uint(x);
  u += 0x7FFFu + ((u >> 16) & 1u);
  return (unsigned short)(u >> 16);
}

// ---- Prep: bf16 weight panel, K-tile-major: Btt[kk][272 cols][32 k] ----
__global__ __launch_bounds__(256) void bt_prep_kernel(
    const float* __restrict__ Wsrc, const float* __restrict__ Wdst,
    const float* __restrict__ Wasrc, const float* __restrict__ Wadst,
    unsigned short* __restrict__ Btt)
{
  int c = blockIdx.x;     // 0..271 (output column)
  int k = threadIdx.x;    // 0..255 (reduction index)
  float v = 0.f;
  if (c < 128)      v = Wsrc[(size_t)k * HF + c];
  else if (c < 256) v = Wdst[(size_t)k * HF + (c - 128)];
  else if (c < 260) v = Wasrc[(size_t)k * HH + (c - 256)];
  else if (c < 264) v = Wadst[(size_t)k * HH + (c - 260)];
  int kk = k >> 5, k5 = k & 31;
  Btt[(size_t)kk * (NCOL * 32) + c * 32 + k5] = bf16r(v);
}

// ---- Prep: transposed bf16 W_agg [128][128] and W_apply [32][128] ----
__global__ __launch_bounds__(128) void wfin_prep_kernel(
    const float* __restrict__ W_agg, const float* __restrict__ W_apply,
    unsigned short* __restrict__ Wagg_t, unsigned short* __restrict__ Wapp_t)
{
  int c = blockIdx.x;     // 0..159
  int k = threadIdx.x;    // 0..127
  if (c < 128) Wagg_t[(size_t)c * HF + k] = bf16r(W_agg[(size_t)k * HF + c]);
  else         Wapp_t[(size_t)(c - 128) * HF + k] = bf16r(W_apply[(size_t)k * OUTD + (c - 128)]);
}

// ---- Kernel 1''': MFMA proj; double-buffered T14 staging, 8 waves ----
// wave w: row-tile r=w>>1, col parity p=w&1 (col-tiles p, p+2, ... < 17).
// Per K-step: issue next-tile global loads -> MFMAs -> ds_write -> 1 barrier.
__global__ __launch_bounds__(512) void mfma_proj_kernel(
    const float* __restrict__ feat, const unsigned short* __restrict__ Btt,
    const float* __restrict__ bdst,
    float* __restrict__ fc_src, float* __restrict__ fc_dst,
    float* __restrict__ asrc, float* __restrict__ adst)
{
  __shared__ unsigned short Albuf[BM * APAD];          // 33792 B
  __shared__ unsigned short Btbuf[2][NCOL * BTPAD];    // 2 x 21760 B
  const int tid  = threadIdx.x;
  const int wave = tid >> 6, lane = tid & 63;
  const int m0 = blockIdx.x * BM;

  // stage A panel [64][256] fp32->bf16
  for (int i = tid; i < BM * 64; i += 512) {
    int r = i >> 6, c4 = i & 63;
    int gr = m0 + r; if (gr >= NN) gr = NN - 1;
    float4 v = *(const float4*)(feat + (size_t)gr * DD + c4 * 4);
    us4 b; b.x = bf16r(v.x); b.y = bf16r(v.y); b.z = bf16r(v.z); b.w = bf16r(v.w);
    *(us4*)&Albuf[r * APAD + c4 * 4] = b;
  }

  // staging chunk ownership (short8 units within one tile: 1088)
  const int ch0 = tid, ch1 = tid + 512, ch2 = tid + 1024;  // ch2 valid iff tid < 64
  const short8* Bs8 = (const short8*)Btt;
  short8 st0, st1, st2;

  // prologue: tile 0 -> buf 0
  st0 = Bs8[ch0]; st1 = Bs8[ch1];
  if (ch2 < TILE_S8) st2 = Bs8[ch2];
  {
    int c, q;
    c = ch0 >> 2; q = ch0 & 3; *(short8*)&Btbuf[0][c * BTPAD + q * 8] = st0;
    c = ch1 >> 2; q = ch1 & 3; *(short8*)&Btbuf[0][c * BTPAD + q * 8] = st1;
    if (ch2 < TILE_S8) { c = ch2 >> 2; q = ch2 & 3; *(short8*)&Btbuf[0][c * BTPAD + q * 8] = st2; }
  }
  __syncthreads();

  const int r = wave >> 1, p = wave & 1;
  const int arow = r * 16 + (lane & 15);
  const int koff = (lane >> 4) * 8;
  const int cl = lane & 15;

  f32x4 acc[9];
#pragma unroll
  for (int t = 0; t < 9; ++t) acc[t] = (f32x4){0.f, 0.f, 0.f, 0.f};

  for (int kk = 0; kk < 8; ++kk) {
    const int cur = kk & 1;
    if (kk < 7) {                      // issue next tile's loads (latency hides under MFMAs)
      const short8* src = Bs8 + (size_t)(kk + 1) * TILE_S8;
      st0 = src[ch0]; st1 = src[ch1];
      if (ch2 < TILE_S8) st2 = src[ch2];
    }
    short8 a = *(const short8*)&Albuf[arow * APAD + kk * 32 + koff];
#pragma unroll
    for (int t = 0; t < 9; ++t) {
      int c0 = p + 2 * t;
      if (c0 < 17) {
        short8 b = *(const short8*)&Btbuf[cur][(c0 * 16 + cl) * BTPAD + koff];
        acc[t] = __builtin_amdgcn_mfma_f32_16x16x32_bf16(a, b, acc[t], 0, 0, 0);
      }
    }
    if (kk < 7) {                      // write-late into the other buffer
      int c, q; const int nb = cur ^ 1;
      c = ch0 >> 2; q = ch0 & 3; *(short8*)&Btbuf[nb][c * BTPAD + q * 8] = st0;
      c = ch1 >> 2; q = ch1 & 3; *(short8*)&Btbuf[nb][c * BTPAD + q * 8] = st1;
      if (ch2 < TILE_S8) { c = ch2 >> 2; q = ch2 & 3; *(short8*)&Btbuf[nb][c * BTPAD + q * 8] = st2; }
    }
    __syncthreads();
  }

  const int rbase = m0 + r * 16 + (lane >> 4) * 4;
#pragma unroll
  for (int t = 0; t < 9; ++t) {
    int c0 = p + 2 * t;
    if (c0 >= 17) break;
    int gcol = c0 * 16 + cl;
#pragma unroll
    for (int j = 0; j < 4; ++j) {
      int grow = rbase + j;
      if (grow >= NN) continue;
      float v = acc[t][j];
      if (gcol < 128)      fc_src[(size_t)grow * HF + gcol] = v;
      else if (gcol < 256) fc_dst[(size_t)grow * HF + (gcol - 128)] = v + bdst[gcol - 128];
      else if (gcol < 260) asrc[(size_t)grow * HH + (gcol - 256)] = v;
      else if (gcol < 264) adst[(size_t)grow * HH + (gcol - 260)] = v;
    }
  }
}

// ---- dst-degree histogram + per-edge rank (CSR slot precompute) ----
__global__ __launch_bounds__(256) void hist_kernel(
    const int* __restrict__ dst_idx, int* __restrict__ cnt,
    int* __restrict__ rank)
{
  int e = blockIdx.x * 256 + threadIdx.x;
  if (e < NE) rank[e] = atomicAdd(&cnt[dst_idx[e]], 1);
}

// ---- CSR scan: block-local exclusive scan ----
__global__ __launch_bounds__(256) void scan_block_kernel(
    const int* __restrict__ cnt, int* __restrict__ offs, int* __restrict__ bsum)
{
  __shared__ int tmp[256];
  int t = threadIdx.x;
  int i = blockIdx.x * 256 + t;
  int v = (i < NN) ? cnt[i] : 0;
  tmp[t] = v;
  __syncthreads();
  for (int ofs = 1; ofs < 256; ofs <<= 1) {
    int add = (t >= ofs) ? tmp[t - ofs] : 0;
    __syncthreads();
    tmp[t] += add;
    __syncthreads();
  }
  if (i < NN) offs[i] = tmp[t] - v;
  if (t == 255) bsum[blockIdx.x] = tmp[255];
}

__global__ __launch_bounds__(256) void scan_bsum_kernel(
    const int* __restrict__ bsum, int* __restrict__ boff)
{
  __shared__ int tmp[256];
  int t = threadIdx.x;
  int v = (t < NB_SCAN) ? bsum[t] : 0;
  tmp[t] = v;
  __syncthreads();
  for (int ofs = 1; ofs < 256; ofs <<= 1) {
    int add = (t >= ofs) ? tmp[t - ofs] : 0;
    __syncthreads();
    tmp[t] += add;
    __syncthreads();
  }
  if (t < NB_SCAN) boff[t] = tmp[t] - v;
}

__global__ __launch_bounds__(256) void scan_final_kernel(
    int* __restrict__ offs, const int* __restrict__ boff)
{
  int i = blockIdx.x * 256 + threadIdx.x;
  if (i < NN) offs[i] += boff[blockIdx.x];
  if (i == 0) offs[NN] = NE;
}

// ---- fused: per-edge logits + scatter into CSR slot (no atomics) ----
__global__ __launch_bounds__(256) void scatter_logits_kernel(
    const float* __restrict__ feat_edge, const float* __restrict__ Wae, // [16,4]
    const int* __restrict__ src_idx, const int* __restrict__ dst_idx,
    const float* __restrict__ asrc, const float* __restrict__ adst,
    const int* __restrict__ offs, const int* __restrict__ rank,
    int* __restrict__ src_sorted, float* __restrict__ esorted)
{
  int e = blockIdx.x * 256 + threadIdx.x;
  if (e >= NE) return;
  int s = src_idx[e], d = dst_idx[e];

  float ae[HH] = {0.f, 0.f, 0.f, 0.f};
  const float4* fe4 = (const float4*)(feat_edge + (size_t)e * DE_DIM);
#pragma unroll
  for (int q = 0; q < 4; ++q) {
    float4 x = fe4[q];
    const float xs[4] = {x.x, x.y, x.z, x.w};
#pragma unroll
    for (int kk = 0; kk < 4; ++kk) {
      int k = q * 4 + kk;
#pragma unroll
      for (int h = 0; h < HH; ++h) ae[h] += xs[kk] * Wae[k * HH + h];
    }
  }
  float as[4], ad[4];
  *(float4*)as = *(const float4*)(asrc + (size_t)s * 4);
  *(float4*)ad = *(const float4*)(adst + (size_t)d * 4);

  float ev[4];
#pragma unroll
  for (int h = 0; h < HH; ++h) {
    float v = as[h] + ad[h] + ae[h];
    ev[h] = v >= 0.f ? v : SLOPE * v;
  }
  int p = offs[d] + rank[e];
  src_sorted[p] = s;
  *(float4*)(esorted + (size_t)p * 4) = *(float4*)ev;
}

// ---- fused segment softmax + aggregation: one wave per dst node ----
__global__ __launch_bounds__(64) void agg_fused_kernel(
    const int* __restrict__ offs, const int* __restrict__ src_sorted,
    const float* __restrict__ esorted, const float* __restrict__ fc_src,
    float* __restrict__ h_out)
{
  const int d = blockIdx.x;
  const int t = threadIdx.x;        // 0..63
  const int fpair = t << 1;         // feature base (even)
  const int h = t >> 4;             // head, 16 lanes each
  const int beg = offs[d], end = offs[d + 1];

  float m = -3.4e38f;
  for (int p = beg + (t & 15); p < end; p += 16)
    m = fmaxf(m, esorted[(size_t)p * 4 + h]);
#pragma unroll
  for (int ofs = 1; ofs < 16; ofs <<= 1)
    m = fmaxf(m, __shfl_xor(m, ofs, 16));

  float ssum = 0.f;
  float accx = 0.f, accy = 0.f;
  int p = beg;
  for (; p + 4 <= end; p += 4) {
    int s0 = src_sorted[p + 0];
    int s1 = src_sorted[p + 1];
    int s2 = src_sorted[p + 2];
    int s3 = src_sorted[p + 3];
    float e0 = esorted[(size_t)(p + 0) * 4 + h];
    float e1 = esorted[(size_t)(p + 1) * 4 + h];
    float e2 = esorted[(size_t)(p + 2) * 4 + h];
    float e3 = esorted[(size_t)(p + 3) * 4 + h];
    float2 fa = *(const float2*)&fc_src[(size_t)s0 * HF + fpair];
    float2 fb = *(const float2*)&fc_src[(size_t)s1 * HF + fpair];
    float2 fc_ = *(const float2*)&fc_src[(size_t)s2 * HF + fpair];
    float2 fd = *(const float2*)&fc_src[(size_t)s3 * HF + fpair];
    float z0 = __expf(e0 - m), z1 = __expf(e1 - m);
    float z2 = __expf(e2 - m), z3 = __expf(e3 - m);
    ssum += (z0 + z1) + (z2 + z3);
    accx += fa.x * z0 + fb.x * z1 + fc_.x * z2 + fd.x * z3;
    accy += fa.y * z0 + fb.y * z1 + fc_.y * z2 + fd.y * z3;
  }
  for (; p < end; ++p) {
    int s = src_sorted[p];
    float z = __expf(esorted[(size_t)p * 4 + h] - m);
    float2 f = *(const float2*)&fc_src[(size_t)s * HF + fpair];
    ssum += z;
    accx += f.x * z;
    accy += f.y * z;
  }
  float inv = (end > beg) ? 1.f / ssum : 0.f;
  float2 rr; rr.x = accx * inv; rr.y = accy * inv;
  *(float2*)&h_out[(size_t)d * HF + fpair] = rr;
}

// ---- Kernel 5': LN + MFMA(W_agg) + residual/leaky + MFMA(W_apply) ----
__global__ __launch_bounds__(256) void node_final_mfma_kernel(
    const float* __restrict__ h_in, const float* __restrict__ scale,
    const float* __restrict__ offset,
    const unsigned short* __restrict__ Wagg_t, const float* __restrict__ b_agg,
    const float* __restrict__ fc_dst,
    const unsigned short* __restrict__ Wapp_t, const float* __restrict__ b_apply,
    float* __restrict__ out)
{
  __shared__ unsigned short Abuf[NFB * FPAD];     // 17408 B
  __shared__ unsigned short A2buf[NFB * FPAD];    // 17408 B
  __shared__ unsigned short Bagg[HF * FPAD];      // 34816 B
  __shared__ unsigned short Bapp[OUTD * FPAD];    // 8704 B
  const int tid = threadIdx.x;
  const int wave = tid >> 6, lane = tid & 63;
  const int n0 = blockIdx.x * NFB;

  for (int i = tid; i < HF * 16; i += 256) {
    int c = i >> 4, q = i & 15;
    *(short8*)&Bagg[c * FPAD + q * 8] = *(const short8*)(Wagg_t + (size_t)c * HF + q * 8);
  }
  for (int i = tid; i < OUTD * 16; i += 256) {
    int c = i >> 4, q = i & 15;
    *(short8*)&Bapp[c * FPAD + q * 8] = *(const short8*)(Wapp_t + (size_t)c * HF + q * 8);
  }

  {
    const int half = tid >> 7;        // 0/1
    const int t = tid & 127;          // feature
    const float sc = scale[t], of = offset[t];
    for (int nn = 0; nn < 32; ++nn) {
      int row = half * 32 + nn;
      int node = n0 + row; if (node >= NN) node = NN - 1;
      float v = h_in[(size_t)node * HF + t];
      float sum = v;
#pragma unroll
      for (int m = 1; m < 32; m <<= 1) sum += __shfl_xor(sum, m);
      float mean = sum * (1.f / 32.f);
      float dv = v - mean;
      float v2 = dv * dv;
#pragma unroll
      for (int m = 1; m < 32; m <<= 1) v2 += __shfl_xor(v2, m);
      float var = v2 * (1.f / 32.f) + 1e-9f;
      Abuf[row * FPAD + t] = bf16r(dv * sc * rsqrtf(var) + of);
    }
  }
  __syncthreads();

  const int arow = wave * 16 + (lane & 15);
  const int koff = (lane >> 4) * 8;
  const int rbase = wave * 16 + (lane >> 4) * 4;
  const int cl = lane & 15;

  f32x4 acc1[8];
#pragma unroll
  for (int c0 = 0; c0 < 8; ++c0) acc1[c0] = (f32x4){0.f, 0.f, 0.f, 0.f};
#pragma unroll
  for (int ks = 0; ks < 4; ++ks) {
    short8 a = *(const short8*)&Abuf[arow * FPAD + ks * 32 + koff];
#pragma unroll
    for (int c0 = 0; c0 < 8; ++c0) {
      short8 b = *(const short8*)&Bagg[(c0 * 16 + cl) * FPAD + ks * 32 + koff];
      acc1[c0] = __builtin_amdgcn_mfma_f32_16x16x32_bf16(a, b, acc1[c0], 0, 0, 0);
    }
  }

#pragma unroll
  for (int c0 = 0; c0 < 8; ++c0) {
    int gcol = c0 * 16 + cl;
    float bg = b_agg[gcol];
#pragma unroll
    for (int j = 0; j < 4; ++j) {
      int row = rbase + j;
      int grow = n0 + row;
      float fd = (grow < NN) ? fc_dst[(size_t)grow * HF + gcol] : 0.f;
      float r = acc1[c0][j] + bg + fd;
      A2buf[row * FPAD + gcol] = bf16r(r >= 0.f ? r : SLOPE * r);
    }
  }
  __syncthreads();

  f32x4 acc2[2];
#pragma unroll
  for (int c0 = 0; c0 < 2; ++c0) acc2[c0] = (f32x4){0.f, 0.f, 0.f, 0.f};
#pragma unroll
  for (int ks = 0; ks < 4; ++ks) {
    short8 a = *(const short8*)&A2buf[arow * FPAD + ks * 32 + koff];
#pragma unroll
    for (int c0 = 0; c0 < 2; ++c0) {
      short8 b = *(const short8*)&Bapp[(c0 * 16 + cl) * FPAD + ks * 32 + koff];
      acc2[c0] = __builtin_amdgcn_mfma_f32_16x16x32_bf16(a, b, acc2[c0], 0, 0, 0);
    }
  }
#pragma unroll
  for (int c0 = 0; c0 < 2; ++c0) {
    int gcol = c0 * 16 + cl;
    float ba = b_apply[gcol];
#pragma unroll
    for (int j = 0; j < 4; ++j) {
      int grow = n0 + rbase + j;
      if (grow < NN) out[(size_t)grow * OUTD + gcol] = acc2[c0][j] + ba;
    }
  }
}

extern "C" void kernel_launch(void* const* d_in, const int* in_sizes, int n_in,
                              void* d_out, int out_size, void* d_ws, size_t ws_size,
                              hipStream_t stream)
{
  const float* feat_src    = (const float*)d_in[0];
  const float* feat_edge   = (const float*)d_in[1];
  const int*   src_idx     = (const int*)d_in[2];
  const int*   dst_idx     = (const int*)d_in[3];
  const float* W_src       = (const float*)d_in[4];
  const float* W_attn_src  = (const float*)d_in[5];
  const float* W_attn_dst  = (const float*)d_in[6];
  const float* W_attn_edge = (const float*)d_in[7];
  const float* scale       = (const float*)d_in[8];
  const float* offset      = (const float*)d_in[9];
  const float* W_agg       = (const float*)d_in[10];
  const float* b_agg       = (const float*)d_in[11];
  const float* W_dst       = (const float*)d_in[12];
  const float* b_dst       = (const float*)d_in[13];
  const float* W_apply     = (const float*)d_in[14];
  const float* b_apply     = (const float*)d_in[15];
  float* out = (float*)d_out;

  char* ws = (char*)d_ws;
  size_t off = 0;
  auto take = [&](size_t bytes) {
    size_t o = off;
    off = (off + bytes + 255) & ~(size_t)255;
    return o;
  };
  size_t fc_src_off = take((size_t)NN * HF * 4);
  size_t fc_dst_off = take((size_t)NN * HF * 4);
  size_t asrc_off   = take((size_t)NN * 4 * 4);
  size_t adst_off   = take((size_t)NN * 4 * 4);
  size_t bt_off     = take((size_t)NCOL * DD * 2);
  size_t wagg_off   = take((size_t)HF * HF * 2);
  size_t wapp_off   = take((size_t)OUTD * HF * 2);
  size_t cnt_off    = take((size_t)NN * 4);       // zeroed
  size_t offs_off   = take((size_t)(NN + 1) * 4);
  size_t bsum_off   = take((size_t)NB_SCAN * 4);
  size_t boff_off   = take((size_t)NB_SCAN * 4);
  size_t rank_off   = take((size_t)NE * 4);
  size_t ssort_off  = take((size_t)NE * 4);
  size_t esort_off  = take((size_t)NE * 4 * 4);
  size_t hout_off   = take((size_t)NN * HF * 4);
  if (ws_size < off) return;  // workspace too small -> loud failure

  float*          fc_src     = (float*)(ws + fc_src_off);
  float*          fc_dst     = (float*)(ws + fc_dst_off);
  float*          asrc       = (float*)(ws + asrc_off);
  float*          adst       = (float*)(ws + adst_off);
  unsigned short* Btt        = (unsigned short*)(ws + bt_off);
  unsigned short* Wagg_t     = (unsigned short*)(ws + wagg_off);
  unsigned short* Wapp_t     = (unsigned short*)(ws + wapp_off);
  int*            cnt        = (int*)(ws + cnt_off);
  int*            offs       = (int*)(ws + offs_off);
  int*            bsum       = (int*)(ws + bsum_off);
  int*            boff       = (int*)(ws + boff_off);
  int*            rank       = (int*)(ws + rank_off);
  int*            src_sorted = (int*)(ws + ssort_off);
  float*          esorted    = (float*)(ws + esort_off);
  float*          h_out      = (float*)(ws + hout_off);

  hipMemsetAsync(ws + cnt_off, 0, (size_t)NN * 4, stream);

  bt_prep_kernel<<<NCOL, 256, 0, stream>>>(W_src, W_dst, W_attn_src, W_attn_dst, Btt);
  wfin_prep_kernel<<<160, 128, 0, stream>>>(W_agg, W_apply, Wagg_t, Wapp_t);

  hist_kernel<<<(NE + 255) / 256, 256, 0, stream>>>(dst_idx, cnt, rank);

  mfma_proj_kernel<<<(NN + BM - 1) / BM, 512, 0, stream>>>(
      feat_src, Btt, b_dst, fc_src, fc_dst, asrc, adst);

  scan_block_kernel<<<NB_SCAN, 256, 0, stream>>>(cnt, offs, bsum);
  scan_bsum_kernel<<<1, 256, 0, stream>>>(bsum, boff);
  scan_final_kernel<<<NB_SCAN, 256, 0, stream>>>(offs, boff);

  scatter_logits_kernel<<<(NE + 255) / 256, 256, 0, stream>>>(
      feat_edge, W_attn_edge, src_idx, dst_idx, asrc, adst,
      offs, rank, src_sorted, esorted);

  agg_fused_kernel<<<NN, 64, 0, stream>>>(
      offs, src_sorted, esorted, fc_src, h_out);

  node_final_mfma_kernel<<<(NN + NFB - 1) / NFB, 256, 0, stream>>>(
      h_out, scale, offset, Wagg_t, b_agg, fc_dst, Wapp_t, b_apply, out);
}